// Round 2
// baseline (622.905 us; speedup 1.0000x reference)
//
#include <hip/hip_runtime.h>
#include <hip/hip_bf16.h>

// Problem constants (AttentionModule: B=16, idf=128, cdf=256, H=W=128, L=64)
#define NB  16
#define IDF 128
#define CDF 256
#define HH  128
#define WWD 128
#define LL  64
#define PP  (HH * WWD)   // 16384 pixels per batch

// ---------------------------------------------------------------------------
// Kernel 0: decode the mask, whatever its device dtype is, into an additive
// float table madd[16*64] (0 = keep, -inf = masked).
// Detection: if the buffer is int32 (bool upcast), bytes at index i%4!=0 are
// all zero. If it's 1-byte bool, ~230 of the ~300 one-bytes land at i%4!=0.
// ---------------------------------------------------------------------------
__global__ void mask_prep_kernel(const unsigned char* __restrict__ mask_raw,
                                 float* __restrict__ madd) {
    __shared__ int is_u8;
    const int k = threadIdx.x;            // 0..1023, one block
    if (k == 0) is_u8 = 0;
    __syncthreads();
    const unsigned char byte = mask_raw[k];
    if ((k & 3) != 0 && byte != 0) atomicOr(&is_u8, 1);
    __syncthreads();
    int masked;
    if (is_u8) masked = (byte != 0);
    else       masked = (((const int*)mask_raw)[k] != 0);
    madd[k] = masked ? -INFINITY : 0.0f;
}

// ---------------------------------------------------------------------------
// Kernel 1: source[b, o, l] = sum_c W[o, c] * context[b, c, l]
// ---------------------------------------------------------------------------
__global__ void src_gemm_kernel(const float* __restrict__ Wm,
                                const float* __restrict__ ctx,
                                float* __restrict__ src) {
    int g = blockIdx.x * 256 + threadIdx.x;      // 0 .. NB*IDF*LL-1
    int l = g & (LL - 1);
    int o = (g >> 6) & (IDF - 1);
    int b = g >> 13;
    const float* wrow = Wm + (size_t)o * CDF;
    const float* ccol = ctx + (size_t)b * CDF * LL + l;
    float s = 0.f;
    #pragma unroll 8
    for (int c = 0; c < CDF; ++c)
        s = fmaf(wrow[c], ccol[(size_t)c * LL], s);
    src[g] = s;
}

// ---------------------------------------------------------------------------
// Kernel 2: per (batch, 256-pixel tile):
//   logits[p, l] = sum_i x[b,i,p] * source[b,i,l]   (source staged in LDS)
//   masked softmax over l  (mask row = p % 16, torch-tile-faithful)
//   attn_out[b,l,p] = prob[l]
//   weight[b,i,p]   = sum_l source[b,i,l] * prob[l]
// ---------------------------------------------------------------------------
__global__ void attn_kernel(const float* __restrict__ x,
                            const float* __restrict__ src,
                            const float* __restrict__ madd_g,
                            float* __restrict__ weight,
                            float* __restrict__ attn_out) {
    __shared__ float s_src[IDF * LL];     // 32 KB
    __shared__ float s_madd[NB * 65];     // pad 65: 16 distinct banks -> broadcast reads

    const int b   = blockIdx.y;
    const int tid = threadIdx.x;

    const float* sb = src + (size_t)b * IDF * LL;
    #pragma unroll
    for (int k = 0; k < (IDF * LL) / 256; ++k)
        s_src[tid + k * 256] = sb[tid + k * 256];
    for (int k = tid; k < NB * LL; k += 256) {
        int row = k >> 6, l = k & 63;
        s_madd[row * 65 + l] = madd_g[k];
    }
    __syncthreads();

    const int p = blockIdx.x * 256 + tid;
    const float* xb = x + (size_t)b * IDF * PP + p;

    float acc[LL];
    #pragma unroll
    for (int l = 0; l < LL; ++l) acc[l] = 0.f;

    // QK^T: stream x down i, one coalesced load per i, prefetched 1 ahead.
    float xv = xb[0];
    for (int i = 0; i < IDF; ++i) {
        float xn = xb[(size_t)((i + 1) & (IDF - 1)) * PP];  // i=127 wraps (harmless)
        const float* srow = &s_src[i * LL];
        #pragma unroll
        for (int l = 0; l < LL; ++l)
            acc[l] = fmaf(xv, srow[l], acc[l]);
        xv = xn;
    }

    // Masked softmax over l (in registers). madd = 0 or -inf.
    const float* madd = &s_madd[(p & (NB - 1)) * 65];
    #pragma unroll
    for (int l = 0; l < LL; ++l) acc[l] += madd[l];
    float mx = -INFINITY;
    #pragma unroll
    for (int l = 0; l < LL; ++l) mx = fmaxf(mx, acc[l]);
    float sum = 0.f;
    #pragma unroll
    for (int l = 0; l < LL; ++l) {
        float e = __expf(acc[l] - mx);   // exp(-inf) = 0 for masked entries
        acc[l] = e;
        sum += e;
    }
    const float inv = 1.f / sum;
    #pragma unroll
    for (int l = 0; l < LL; ++l) acc[l] *= inv;

    // attn_out[b, l, p]
    float* aout = attn_out + (size_t)b * LL * PP + p;
    #pragma unroll
    for (int l = 0; l < LL; ++l) aout[(size_t)l * PP] = acc[l];

    // weight[b, i, p] = sum_l source[b,i,l] * prob[l]
    float* wout = weight + (size_t)b * IDF * PP + p;
    for (int i = 0; i < IDF; ++i) {
        const float* srow = &s_src[i * LL];
        float s0 = 0.f, s1 = 0.f, s2 = 0.f, s3 = 0.f;
        #pragma unroll
        for (int l = 0; l < LL; l += 4) {
            s0 = fmaf(srow[l + 0], acc[l + 0], s0);
            s1 = fmaf(srow[l + 1], acc[l + 1], s1);
            s2 = fmaf(srow[l + 2], acc[l + 2], s2);
            s3 = fmaf(srow[l + 3], acc[l + 3], s3);
        }
        wout[(size_t)i * PP] = (s0 + s1) + (s2 + s3);
    }
}

// ---------------------------------------------------------------------------
extern "C" void kernel_launch(void* const* d_in, const int* in_sizes, int n_in,
                              void* d_out, int out_size, void* d_ws, size_t ws_size,
                              hipStream_t stream) {
    const float*         x        = (const float*)d_in[0];
    const float*         ctx      = (const float*)d_in[1];
    const float*         Wm       = (const float*)d_in[2];
    const unsigned char* mask_raw = (const unsigned char*)d_in[3];

    float* weight   = (float*)d_out;                       // [B, IDF, H, W]
    float* attn_out = weight + (size_t)NB * IDF * PP;      // [B, L, H, W]
    float* src      = (float*)d_ws;                        // [B, IDF, LL] (512 KB)
    float* madd     = src + (size_t)NB * IDF * LL;         // [B*LL] additive mask

    mask_prep_kernel<<<1, NB * LL, 0, stream>>>(mask_raw, madd);
    src_gemm_kernel<<<(NB * IDF * LL) / 256, 256, 0, stream>>>(Wm, ctx, src);

    dim3 grid(PP / 256, NB);
    attn_kernel<<<grid, 256, 0, stream>>>(x, src, madd, weight, attn_out);
}

// Round 3
// 328.398 us; speedup vs baseline: 1.8968x; 1.8968x over previous
//
#include <hip/hip_runtime.h>
#include <hip/hip_bf16.h>

// Problem constants (AttentionModule: B=16, idf=128, cdf=256, H=W=128, L=64)
#define NB  16
#define IDF 128
#define CDF 256
#define HH  128
#define WWD 128
#define LL  64
#define PP  (HH * WWD)   // 16384 pixels per batch

// ---------------------------------------------------------------------------
// Kernel 0: decode the mask (int32 or uint8 on device) into additive floats
// madd[16*64] (0 = keep, -inf = masked).
// ---------------------------------------------------------------------------
__global__ void mask_prep_kernel(const unsigned char* __restrict__ mask_raw,
                                 float* __restrict__ madd) {
    __shared__ int is_u8;
    const int k = threadIdx.x;            // 0..1023, one block
    if (k == 0) is_u8 = 0;
    __syncthreads();
    const unsigned char byte = mask_raw[k];
    if ((k & 3) != 0 && byte != 0) atomicOr(&is_u8, 1);
    __syncthreads();
    int masked;
    if (is_u8) masked = (byte != 0);
    else       masked = (((const int*)mask_raw)[k] != 0);
    madd[k] = masked ? -INFINITY : 0.0f;
}

// ---------------------------------------------------------------------------
// Kernel 1: source[b, o, l] = sum_c W[o, c] * context[b, c, l]
// ---------------------------------------------------------------------------
__global__ void src_gemm_kernel(const float* __restrict__ Wm,
                                const float* __restrict__ ctx,
                                float* __restrict__ src) {
    int g = blockIdx.x * 256 + threadIdx.x;      // 0 .. NB*IDF*LL-1
    int l = g & (LL - 1);
    int o = (g >> 6) & (IDF - 1);
    int b = g >> 13;
    const float* wrow = Wm + (size_t)o * CDF;
    const float* ccol = ctx + (size_t)b * CDF * LL + l;
    float s = 0.f;
    #pragma unroll 8
    for (int c = 0; c < CDF; ++c)
        s = fmaf(wrow[c], ccol[(size_t)c * LL], s);
    src[g] = s;
}

// ---------------------------------------------------------------------------
// Kernel 2: thread = one pixel. source operands are read with WAVE-UNIFORM
// addresses straight from global -> compiler emits s_load + SGPR-operand
// v_fma (scalar-cache broadcast). No LDS staging (LDS->RF writeback was the
// round-2 bottleneck), no 64-float LDS tile, 2-deep x prefetch.
// ---------------------------------------------------------------------------
__global__ __launch_bounds__(256, 4)
void attn_kernel(const float* __restrict__ x,
                 const float* __restrict__ src,
                 const float* __restrict__ madd_g,
                 float* __restrict__ weight,
                 float* __restrict__ attn_out) {
    __shared__ float s_madd[NB * 65];   // pad 65: lane-varying reads, conflict-light

    const int b   = blockIdx.y;
    const int tid = threadIdx.x;

    for (int k = tid; k < NB * LL; k += 256) {
        int row = k >> 6, l = k & 63;
        s_madd[row * 65 + l] = madd_g[k];
    }
    __syncthreads();

    const int p = blockIdx.x * 256 + tid;
    const float* xb = x + (size_t)b * IDF * PP + p;
    const float* sb = src + b * IDF * LL;        // wave-uniform base

    float acc[LL];
    #pragma unroll
    for (int l = 0; l < LL; ++l) acc[l] = 0.f;

    // QK^T: one coalesced x load per i (2-deep prefetch); source row via
    // uniform (scalar) loads feeding the FMA's SGPR operand slot.
    float xv = xb[0];
    float xn = xb[PP];
    for (int i = 0; i < IDF; ++i) {
        float x2 = xb[(size_t)((i + 2) & (IDF - 1)) * PP];  // wraps at end (harmless)
        const int base = i * LL;
        #pragma unroll
        for (int l = 0; l < LL; ++l)
            acc[l] = fmaf(xv, sb[base + l], acc[l]);
        xv = xn;
        xn = x2;
    }

    // Masked softmax over l (registers). madd = 0 or -inf; row = p % 16
    // (torch tile(mask,(P,1)) quirk).
    const float* madd = &s_madd[(p & (NB - 1)) * 65];
    #pragma unroll
    for (int l = 0; l < LL; ++l) acc[l] += madd[l];
    float mx = -INFINITY;
    #pragma unroll
    for (int l = 0; l < LL; ++l) mx = fmaxf(mx, acc[l]);
    float sum = 0.f;
    #pragma unroll
    for (int l = 0; l < LL; ++l) {
        float e = __expf(acc[l] - mx);   // exp(-inf) = 0 for masked entries
        acc[l] = e;
        sum += e;
    }
    const float inv = 1.f / sum;
    #pragma unroll
    for (int l = 0; l < LL; ++l) acc[l] *= inv;

    // attn_out[b, l, p] — coalesced (lane = pixel) per l-plane.
    float* aout = attn_out + (size_t)b * LL * PP + p;
    #pragma unroll
    for (int l = 0; l < LL; ++l) aout[(size_t)l * PP] = acc[l];

    // weight[b, i, p] = sum_l source[b,i,l] * prob[l] — source again via
    // uniform scalar loads (SGPR operand), 4 independent FMA chains.
    float* wout = weight + (size_t)b * IDF * PP + p;
    for (int i = 0; i < IDF; ++i) {
        const int base = i * LL;
        float s0 = 0.f, s1 = 0.f, s2 = 0.f, s3 = 0.f;
        #pragma unroll
        for (int l = 0; l < LL; l += 4) {
            s0 = fmaf(sb[base + l + 0], acc[l + 0], s0);
            s1 = fmaf(sb[base + l + 1], acc[l + 1], s1);
            s2 = fmaf(sb[base + l + 2], acc[l + 2], s2);
            s3 = fmaf(sb[base + l + 3], acc[l + 3], s3);
        }
        wout[(size_t)i * PP] = (s0 + s1) + (s2 + s3);
    }
}

// ---------------------------------------------------------------------------
extern "C" void kernel_launch(void* const* d_in, const int* in_sizes, int n_in,
                              void* d_out, int out_size, void* d_ws, size_t ws_size,
                              hipStream_t stream) {
    const float*         x        = (const float*)d_in[0];
    const float*         ctx      = (const float*)d_in[1];
    const float*         Wm       = (const float*)d_in[2];
    const unsigned char* mask_raw = (const unsigned char*)d_in[3];

    float* weight   = (float*)d_out;                       // [B, IDF, H, W]
    float* attn_out = weight + (size_t)NB * IDF * PP;      // [B, L, H, W]
    float* src      = (float*)d_ws;                        // [B, IDF, LL] (512 KB)
    float* madd     = src + (size_t)NB * IDF * LL;         // [B*LL] additive mask

    mask_prep_kernel<<<1, NB * LL, 0, stream>>>(mask_raw, madd);
    src_gemm_kernel<<<(NB * IDF * LL) / 256, 256, 0, stream>>>(Wm, ctx, src);

    dim3 grid(PP / 256, NB);
    attn_kernel<<<grid, 256, 0, stream>>>(x, src, madd, weight, attn_out);
}

// Round 4
// 151.120 us; speedup vs baseline: 4.1219x; 2.1731x over previous
//
#include <hip/hip_runtime.h>
#include <hip/hip_bf16.h>
#include <hip/hip_fp16.h>

// Problem constants (AttentionModule: B=16, idf=128, cdf=256, H=W=128, L=64)
#define NB  16
#define IDF 128
#define CDF 256
#define LL  64
#define PP  16384      // H*W pixels per batch

typedef _Float16 f16;
typedef _Float16 f16x8 __attribute__((ext_vector_type(8)));
typedef float    f32x4 __attribute__((ext_vector_type(4)));

// ---------------------------------------------------------------------------
// Kernel 0: decode mask (int32 or uint8 on device) -> additive f32 table
// madd[16*64] (0 = keep, -inf = masked). Mask row used by pixel p is p%16
// (torch tile(mask,(P,1)) quirk) — verified passing in rounds 2-3.
// ---------------------------------------------------------------------------
__global__ void mask_prep_kernel(const unsigned char* __restrict__ mask_raw,
                                 float* __restrict__ madd) {
    __shared__ int is_u8;
    const int k = threadIdx.x;            // 0..1023, one block
    if (k == 0) is_u8 = 0;
    __syncthreads();
    const unsigned char byte = mask_raw[k];
    if ((k & 3) != 0 && byte != 0) atomicOr(&is_u8, 1);
    __syncthreads();
    int masked;
    if (is_u8) masked = (byte != 0);
    else       masked = (((const int*)mask_raw)[k] != 0);
    madd[k] = masked ? -INFINITY : 0.0f;
}

// ---------------------------------------------------------------------------
// Kernel 1: source = W @ context (fp32 accum), emitted as fp16 in BOTH
// orientations: srcF[b][i][l] (PV A-operand) and srcT[b][l][i] (QK^T A-op).
// ---------------------------------------------------------------------------
__global__ void src_pack_kernel(const float* __restrict__ Wm,
                                const float* __restrict__ ctx,
                                f16* __restrict__ srcF,
                                f16* __restrict__ srcT) {
    int g = blockIdx.x * 256 + threadIdx.x;      // 0 .. NB*IDF*LL-1
    int l = g & (LL - 1);
    int i = (g >> 6) & (IDF - 1);
    int b = g >> 13;
    const float* wrow = Wm + (size_t)i * CDF;
    const float* ccol = ctx + (size_t)b * CDF * LL + l;
    float s = 0.f;
    #pragma unroll 8
    for (int c = 0; c < CDF; ++c)
        s = fmaf(wrow[c], ccol[(size_t)c * LL], s);
    f16 h = (f16)s;
    srcF[g] = h;                                 // [b][i][l]
    srcT[((size_t)b * LL + l) * IDF + i] = h;    // [b][l][i]
}

// ---------------------------------------------------------------------------
// Kernel 2 (main): one wave = 16 pixels, end to end.
//  QK^T: E[l][p] = sum_i srcT[l][i] * x[i][p] via mfma_f32_16x16x32_f16,
//        M = l (4 mtiles), N = 16 pixels, K = i (4 ksteps).
//        A-frag: srcT global dwordx4 (L2-hot). B-frag: 8 stride-P dword
//        loads of x + cvt to fp16 (each instr = 4 x 64B full sectors).
//  softmax over l: lane holds 16 l's of pixel c; lanes c,c+16,c+32,c+48
//        hold the 4 quarters -> in-lane reduce + 2 shfl_xor. Mask additive.
//  PV:   weight[i][p] = sum_l srcF[i][l] * prob[l][p]; prob goes through a
//        per-wave LDS tile (fp16, pitch 72 -> 16B-aligned b128 reads).
// ---------------------------------------------------------------------------
__global__ __launch_bounds__(256, 4)
void attn_mfma_kernel(const float* __restrict__ x,
                      const f16* __restrict__ srcT,
                      const f16* __restrict__ srcF,
                      const float* __restrict__ madd_g,
                      float* __restrict__ weight,
                      float* __restrict__ attn_out) {
    __shared__ __align__(16) f16   s_prob[4 * 16 * 72];  // per-wave [16 p][72] fp16
    __shared__ __align__(16) float s_madd[16 * 68];      // [row c][68] additive mask

    const int b   = blockIdx.y;
    const int tid = threadIdx.x;
    const int wv   = tid >> 6;         // wave 0..3
    const int lane = tid & 63;
    const int c    = lane & 15;        // pixel column / fragment row
    const int g    = lane >> 4;        // k-slice group 0..3

    // stage additive mask into LDS (pitch 68)
    for (int k = tid; k < NB * LL; k += 256)
        s_madd[(k >> 6) * 68 + (k & 63)] = madd_g[k];
    __syncthreads();

    const int pw = blockIdx.x * 64 + wv * 16;            // wave's pixel base
    const float* xb = x + (size_t)b * IDF * PP + pw + c; // lane's x column

    // ---------------- QK^T ----------------
    const f16* srcT_b = srcT + (size_t)b * LL * IDF;
    f32x4 acc[4];
    #pragma unroll
    for (int mt = 0; mt < 4; ++mt) acc[mt] = (f32x4){0.f, 0.f, 0.f, 0.f};

    #pragma unroll
    for (int ks = 0; ks < 4; ++ks) {
        float xf[8];
        const int i0 = ks * 32 + 8 * g;
        #pragma unroll
        for (int j = 0; j < 8; ++j)
            xf[j] = xb[(size_t)(i0 + j) * PP];
        f16x8 bf;
        #pragma unroll
        for (int j = 0; j < 8; ++j) bf[j] = (f16)xf[j];
        #pragma unroll
        for (int mt = 0; mt < 4; ++mt) {
            const f16x8 af = *reinterpret_cast<const f16x8*>(
                srcT_b + (size_t)(mt * 16 + c) * IDF + i0);
            acc[mt] = __builtin_amdgcn_mfma_f32_16x16x32_f16(af, bf, acc[mt], 0, 0, 0);
        }
    }
    // lane (c,g) now holds E[l][p]: l = mt*16 + 4g + r, p = pw + c.

    // ---------------- masked softmax over l ----------------
    float mx = -INFINITY;
    #pragma unroll
    for (int mt = 0; mt < 4; ++mt) {
        const float4 mv = *reinterpret_cast<const float4*>(
            &s_madd[c * 68 + mt * 16 + 4 * g]);
        acc[mt][0] += mv.x;  acc[mt][1] += mv.y;
        acc[mt][2] += mv.z;  acc[mt][3] += mv.w;
        mx = fmaxf(mx, fmaxf(fmaxf(acc[mt][0], acc[mt][1]),
                             fmaxf(acc[mt][2], acc[mt][3])));
    }
    mx = fmaxf(mx, __shfl_xor(mx, 16, 64));
    mx = fmaxf(mx, __shfl_xor(mx, 32, 64));

    float sum = 0.f;
    #pragma unroll
    for (int mt = 0; mt < 4; ++mt) {
        #pragma unroll
        for (int r = 0; r < 4; ++r) {
            float e = exp2f((acc[mt][r] - mx) * 1.44269504f); // exp(-inf)=0 masked
            acc[mt][r] = e;
            sum += e;
        }
    }
    sum += __shfl_xor(sum, 16, 64);
    sum += __shfl_xor(sum, 32, 64);
    const float inv = 1.f / sum;
    #pragma unroll
    for (int mt = 0; mt < 4; ++mt) {
        acc[mt][0] *= inv; acc[mt][1] *= inv;
        acc[mt][2] *= inv; acc[mt][3] *= inv;
    }

    // attn_out[b][l][p] stores (4 x 64B full sectors per instr)
    float* ab = attn_out + (size_t)b * LL * PP + pw + c;
    #pragma unroll
    for (int mt = 0; mt < 4; ++mt)
        #pragma unroll
        for (int r = 0; r < 4; ++r)
            ab[(size_t)(mt * 16 + 4 * g + r) * PP] = acc[mt][r];

    // prob -> fp16 per-wave LDS tile [p=c][l], pitch 72 (16B-aligned rows)
    f16* pl = s_prob + wv * (16 * 72) + c * 72;
    #pragma unroll
    for (int mt = 0; mt < 4; ++mt) {
        union { f16 h[2]; unsigned u; } z0, z1;
        z0.h[0] = (f16)acc[mt][0];  z0.h[1] = (f16)acc[mt][1];
        z1.h[0] = (f16)acc[mt][2];  z1.h[1] = (f16)acc[mt][3];
        uint2 uu; uu.x = z0.u; uu.y = z1.u;
        *reinterpret_cast<uint2*>(pl + mt * 16 + 4 * g) = uu;  // l = mt*16+4g..+3
    }
    // same-wave LDS exchange: DS ops complete in order per wave; compiler
    // inserts lgkmcnt for the may-alias dependency. No barrier needed.

    // ---------------- PV ----------------
    const f16* srcF_b = srcF + (size_t)b * IDF * LL;
    f32x4 acc2[8];
    #pragma unroll
    for (int mt = 0; mt < 8; ++mt) acc2[mt] = (f32x4){0.f, 0.f, 0.f, 0.f};

    #pragma unroll
    for (int ks = 0; ks < 2; ++ks) {
        const f16x8 bf2 = *reinterpret_cast<const f16x8*>(pl + ks * 32 + 8 * g);
        #pragma unroll
        for (int mt = 0; mt < 8; ++mt) {
            const f16x8 af2 = *reinterpret_cast<const f16x8*>(
                srcF_b + (size_t)(mt * 16 + c) * LL + ks * 32 + 8 * g);
            acc2[mt] = __builtin_amdgcn_mfma_f32_16x16x32_f16(af2, bf2, acc2[mt], 0, 0, 0);
        }
    }

    // weight[b][i][p] stores
    float* wb = weight + (size_t)b * IDF * PP + pw + c;
    #pragma unroll
    for (int mt = 0; mt < 8; ++mt)
        #pragma unroll
        for (int r = 0; r < 4; ++r)
            wb[(size_t)(mt * 16 + 4 * g + r) * PP] = acc2[mt][r];
}

// ---------------------------------------------------------------------------
extern "C" void kernel_launch(void* const* d_in, const int* in_sizes, int n_in,
                              void* d_out, int out_size, void* d_ws, size_t ws_size,
                              hipStream_t stream) {
    const float*         x        = (const float*)d_in[0];
    const float*         ctx      = (const float*)d_in[1];
    const float*         Wm       = (const float*)d_in[2];
    const unsigned char* mask_raw = (const unsigned char*)d_in[3];

    float* weight   = (float*)d_out;                     // [B, IDF, H, W]
    float* attn_out = weight + (size_t)NB * IDF * PP;    // [B, L, H, W]

    // workspace: madd (4KB) | srcF fp16 (256KB) | srcT fp16 (256KB)
    float* madd = (float*)d_ws;
    f16*   srcF = (f16*)((char*)d_ws + 4096);
    f16*   srcT = srcF + (size_t)NB * IDF * LL;

    mask_prep_kernel<<<1, NB * LL, 0, stream>>>(mask_raw, madd);
    src_pack_kernel<<<(NB * IDF * LL) / 256, 256, 0, stream>>>(Wm, ctx, srcF, srcT);

    dim3 grid(PP / 64, NB);
    attn_mfma_kernel<<<grid, 256, 0, stream>>>(x, srcT, srcF, madd, weight, attn_out);
}